// Round 5
// baseline (30.247 us; speedup 1.0000x reference)
//
#include <hip/hip_runtime.h>

#define NPTS 16384

typedef short bf16x8 __attribute__((ext_vector_type(8)));
typedef float f32x16 __attribute__((ext_vector_type(16)));
typedef unsigned short us8v __attribute__((ext_vector_type(8)));

__device__ __forceinline__ unsigned short f2bf(float x) {
  unsigned int u = __float_as_uint(x);
  u = (u + 0x7FFFu + ((u >> 16) & 1u)) >> 16;   // RNE
  return (unsigned short)u;
}
__device__ __forceinline__ float bf2f(unsigned short h) {
  return __uint_as_float(((unsigned int)h) << 16);
}

// F features for one B-point (identical encoding to the verified round-3/4
// prepack): h0 = {xh,xh,xl,xl, yh,yh,yl,yl} of -2p; h1 = {zh,zh,zl,zl,
// whi,wmid,wlo, 0} with w = |p|^2 split 3-way.  Paired with G =
// {xh,xl,xh,xl, yh,yl,yh,yl | zh,zl,zh,zl, 1,1,1,0}: F.G = |p|^2 - 2 p.q.
__device__ __forceinline__ void buildF(float x, float y, float z,
                                       us8v& h0, us8v& h1) {
  float t;
  t = -2.0f * x; const unsigned short xh = f2bf(t), xl = f2bf(t - bf2f(xh));
  t = -2.0f * y; const unsigned short yh = f2bf(t), yl = f2bf(t - bf2f(yh));
  t = -2.0f * z; const unsigned short zh = f2bf(t), zl = f2bf(t - bf2f(zh));
  const float w = x * x + y * y + z * z;
  const unsigned short wh = f2bf(w);
  const float w1 = w - bf2f(wh);
  const unsigned short wm = f2bf(w1);
  const unsigned short wl = f2bf(w1 - bf2f(wm));
  h0[0] = xh; h0[1] = xh; h0[2] = xl; h0[3] = xl;
  h0[4] = yh; h0[5] = yh; h0[6] = yl; h0[7] = yl;
  h1[0] = zh; h1[1] = zh; h1[2] = zl; h1[3] = zl;
  h1[4] = wh; h1[5] = wm; h1[6] = wl; h1[7] = 0;
}

// ---------------------------------------------------------------------------
// Fused kernel. grid = 512 = dir(2) x ag(32) x cc(8); 256 thr = 4 waves.
// Block: 512 A-points (4 waves x 4 tiles x 32), B-chunk 2048 pts in 2 rounds
// of 1024. F computed in-block from raw points (no prepack dispatch).
// LDS slot layout (point-permuted; min over rows is permutation-invariant):
//   half h of point 4t+i lives at byte h*16384 + i*4096 + t*16
//   -> writes: 8 x ds_write_b128, wave-contiguous, conflict-free
//   -> reads:  lane l, group g at h=(l>>5)*16384 + g*512 + (l&31)*16
//              (lanes l, l+32 alias banks 2-way = free)
// Inner loop per wave: 1 ds_read_b128 + 4 mfma_32x32x16_bf16 + 32 v_min3.
// Output: per-chunk per-point min as bf16 -> partial[2*NPTS][8] (no atomics).
// ---------------------------------------------------------------------------
__global__ __launch_bounds__(256, 2) void chamfer_fused_kernel(
    const float* __restrict__ adv, const float* __restrict__ ori,
    unsigned short* __restrict__ partial /* [2*NPTS][8] bf16 */) {
  __shared__ short lds[2][16384];  // 2 x 32 KB round buffers

  const int bid = blockIdx.x;
  const int dir = bid >> 8;
  const int rr  = bid & 255;
  const int ag  = rr >> 3;   // 0..31 A-group (512 pts)
  const int cc  = rr & 7;    // 0..7  B-chunk (2048 pts)

  const float* __restrict__ A = dir ? ori : adv;
  const float* __restrict__ B = dir ? adv : ori;

  const int tid  = threadIdx.x;  // 0..255
  const int wv   = tid >> 6;
  const int lane = tid & 63;
  const int col  = lane & 31;
  const int half = lane >> 5;

  // ---- issue raw B loads for both rounds (3 x float4 per thread each) ----
  const float* braw = B + (size_t)(cc * 2048) * 3;
  const float4* p40 = (const float4*)(braw + (size_t)(4 * tid) * 3);
  const float4* p41 = (const float4*)(braw + (size_t)(1024 + 4 * tid) * 3);
  const float4 r0a = p40[0], r0b = p40[1], r0c = p40[2];
  const float4 r1a = p41[0], r1b = p41[1], r1c = p41[2];

  // ---- G fragments (MFMA B-operand) for this wave's 4 A-tiles ----
  const unsigned short ONE = 0x3F80;
  bf16x8 g0, g1, g2, g3;
  float q2[4];
  int q[4];
#pragma unroll
  for (int i = 0; i < 4; ++i) {
    const int qi = ag * 512 + wv * 128 + i * 32 + col;
    q[i] = qi;
    const float x = A[qi * 3], y = A[qi * 3 + 1], z = A[qi * 3 + 2];
    q2[i] = x * x + y * y + z * z;
    const unsigned short xh = f2bf(x), xl = f2bf(x - bf2f(xh));
    const unsigned short yh = f2bf(y), yl = f2bf(y - bf2f(yh));
    const unsigned short zh = f2bf(z), zl = f2bf(z - bf2f(zh));
    bf16x8 g;
    g[0] = half ? zh : xh; g[1] = half ? zl : xl;
    g[2] = half ? zh : xh; g[3] = half ? zl : xl;
    g[4] = half ? ONE : yh; g[5] = half ? ONE : yl;
    g[6] = half ? ONE : yh; g[7] = half ? (unsigned short)0 : yl;
    if (i == 0) g0 = g; else if (i == 1) g1 = g;
    else if (i == 2) g2 = g; else g3 = g;
  }

  // points of float4-triple (a,b,c): p0=(a.x,a.y,a.z) p1=(a.w,b.x,b.y)
  // p2=(b.z,b.w,c.x) p3=(c.y,c.z,c.w)
  auto writeF = [&](int buf, float4 a, float4 b, float4 c) {
    char* base = (char*)&lds[buf][0] + tid * 16;
    us8v h0, h1;
    buildF(a.x, a.y, a.z, h0, h1);
    *(us8v*)(base + 0 * 4096) = h0; *(us8v*)(base + 16384 + 0 * 4096) = h1;
    buildF(a.w, b.x, b.y, h0, h1);
    *(us8v*)(base + 1 * 4096) = h0; *(us8v*)(base + 16384 + 1 * 4096) = h1;
    buildF(b.z, b.w, c.x, h0, h1);
    *(us8v*)(base + 2 * 4096) = h0; *(us8v*)(base + 16384 + 2 * 4096) = h1;
    buildF(c.y, c.z, c.w, h0, h1);
    *(us8v*)(base + 3 * 4096) = h0; *(us8v*)(base + 16384 + 3 * 4096) = h1;
  };

  const f32x16 zacc = {};
  float m0a = 1e30f, m0b = 1e30f, m1a = 1e30f, m1b = 1e30f;
  float m2a = 1e30f, m2b = 1e30f, m3a = 1e30f, m3b = 1e30f;

  auto mfmaRound = [&](int buf) {
    const char* Lb = (const char*)&lds[buf][0] + half * 16384 + col * 16;
    bf16x8 f = *(const bf16x8*)(Lb);
#pragma unroll 4
    for (int gg = 0; gg < 32; ++gg) {
      const bf16x8 fn = *(const bf16x8*)(Lb + ((gg + 1) & 31) * 512);
      const f32x16 a0 = __builtin_amdgcn_mfma_f32_32x32x16_bf16(f, g0, zacc, 0, 0, 0);
      const f32x16 a1 = __builtin_amdgcn_mfma_f32_32x32x16_bf16(f, g1, zacc, 0, 0, 0);
      const f32x16 a2 = __builtin_amdgcn_mfma_f32_32x32x16_bf16(f, g2, zacc, 0, 0, 0);
      const f32x16 a3 = __builtin_amdgcn_mfma_f32_32x32x16_bf16(f, g3, zacc, 0, 0, 0);
      m0a = fminf(fminf(m0a, a0[0]), a0[1]);  m0a = fminf(fminf(m0a, a0[2]), a0[3]);
      m0a = fminf(fminf(m0a, a0[4]), a0[5]);  m0a = fminf(fminf(m0a, a0[6]), a0[7]);
      m0b = fminf(fminf(m0b, a0[8]), a0[9]);  m0b = fminf(fminf(m0b, a0[10]), a0[11]);
      m0b = fminf(fminf(m0b, a0[12]), a0[13]); m0b = fminf(fminf(m0b, a0[14]), a0[15]);
      m1a = fminf(fminf(m1a, a1[0]), a1[1]);  m1a = fminf(fminf(m1a, a1[2]), a1[3]);
      m1a = fminf(fminf(m1a, a1[4]), a1[5]);  m1a = fminf(fminf(m1a, a1[6]), a1[7]);
      m1b = fminf(fminf(m1b, a1[8]), a1[9]);  m1b = fminf(fminf(m1b, a1[10]), a1[11]);
      m1b = fminf(fminf(m1b, a1[12]), a1[13]); m1b = fminf(fminf(m1b, a1[14]), a1[15]);
      m2a = fminf(fminf(m2a, a2[0]), a2[1]);  m2a = fminf(fminf(m2a, a2[2]), a2[3]);
      m2a = fminf(fminf(m2a, a2[4]), a2[5]);  m2a = fminf(fminf(m2a, a2[6]), a2[7]);
      m2b = fminf(fminf(m2b, a2[8]), a2[9]);  m2b = fminf(fminf(m2b, a2[10]), a2[11]);
      m2b = fminf(fminf(m2b, a2[12]), a2[13]); m2b = fminf(fminf(m2b, a2[14]), a2[15]);
      m3a = fminf(fminf(m3a, a3[0]), a3[1]);  m3a = fminf(fminf(m3a, a3[2]), a3[3]);
      m3a = fminf(fminf(m3a, a3[4]), a3[5]);  m3a = fminf(fminf(m3a, a3[6]), a3[7]);
      m3b = fminf(fminf(m3b, a3[8]), a3[9]);  m3b = fminf(fminf(m3b, a3[10]), a3[11]);
      m3b = fminf(fminf(m3b, a3[12]), a3[13]); m3b = fminf(fminf(m3b, a3[14]), a3[15]);
      f = fn;
    }
  };

  // ---- pipeline: F(0)->buf0 | barrier | F(1)->buf1, MFMA(buf0) | barrier |
  //      MFMA(buf1) ----
  writeF(0, r0a, r0b, r0c);
  __syncthreads();
  writeF(1, r1a, r1b, r1c);   // overlaps with MFMA(buf0) scheduling
  mfmaRound(0);
  __syncthreads();
  mfmaRound(1);

  // ---- epilogue: fold halves, add |q|^2, write bf16 chunk-min slot ----
  float mc[4];
  mc[0] = fminf(m0a, m0b); mc[1] = fminf(m1a, m1b);
  mc[2] = fminf(m2a, m2b); mc[3] = fminf(m3a, m3b);
#pragma unroll
  for (int i = 0; i < 4; ++i) {
    float m = fminf(mc[i], __shfl_xor(mc[i], 32));
    const float d = fmaxf(m + q2[i], 0.0f);
    if (half == 0)
      partial[(size_t)(dir * NPTS + q[i]) * 8 + cc] = f2bf(d);
  }
}

// ---------------------------------------------------------------------------
// Reduce: single block, 1024 thr. One uint4 = one point's 8 bf16 chunk-mins.
// min-fold 8, accumulate fp32, LDS tree, /NPTS.
// ---------------------------------------------------------------------------
__device__ __forceinline__ float bflo(unsigned int u) {
  return __uint_as_float(u << 16);
}
__device__ __forceinline__ float bfhi(unsigned int u) {
  return __uint_as_float(u & 0xFFFF0000u);
}

__global__ __launch_bounds__(1024) void chamfer_reduce_bf16_kernel(
    const unsigned short* __restrict__ partial, float* __restrict__ out) {
  __shared__ float red[1024];
  const int tid = threadIdx.x;
  const uint4* p4 = (const uint4*)partial;
  float s = 0.0f;
#pragma unroll 8
  for (int it = 0; it < 32; ++it) {
    const uint4 v = p4[it * 1024 + tid];
    float m = fminf(fminf(bflo(v.x), bfhi(v.x)), fminf(bflo(v.y), bfhi(v.y)));
    m = fminf(m, fminf(bflo(v.z), bfhi(v.z)));
    m = fminf(m, fminf(bflo(v.w), bfhi(v.w)));
    s += m;
  }
  red[tid] = s;
  __syncthreads();
  for (int off = 512; off > 0; off >>= 1) {
    if (tid < off) red[tid] += red[tid + off];
    __syncthreads();
  }
  if (tid == 0) out[0] = red[0] * (1.0f / (float)NPTS);  // LOSS_WEIGHT = 1
}

// ---------------------------------------------------------------------------
// Fallback (ws too small): round-2 VALU kernel + uint reduce.
// ---------------------------------------------------------------------------
__global__ __launch_bounds__(256) void chamfer_valu_kernel(
    const float* __restrict__ adv, const float* __restrict__ ori,
    unsigned int* __restrict__ minbuf) {
  __shared__ float4 bt[512];
  const int bx = blockIdx.x;
  const int c = bx & 31;
  const int t = bx >> 5;
  const int dir = t & 1;
  const int ab = t >> 1;
  const float* __restrict__ A = dir ? ori : adv;
  const float* __restrict__ B = dir ? adv : ori;
  const int tid = threadIdx.x;
  for (int j = tid; j < 512; j += 256) {
    const float* bp = B + (size_t)(c * 512 + j) * 3;
    const float x = bp[0], y = bp[1], z = bp[2];
    bt[j] = make_float4(x, y, z, 0.5f * (x * x + y * y + z * z));
  }
  float nax[8], nay[8], naz[8], a2[8], mn[8];
#pragma unroll
  for (int k = 0; k < 8; ++k) {
    const int idx = ab * 2048 + k * 256 + tid;
    const float* ap = A + (size_t)idx * 3;
    const float x = ap[0], y = ap[1], z = ap[2];
    nax[k] = -x; nay[k] = -y; naz[k] = -z;
    a2[k] = x * x + y * y + z * z;
    mn[k] = 1e30f;
  }
  __syncthreads();
#pragma unroll 4
  for (int j = 0; j < 512; j += 2) {
    const float4 b0 = bt[j];
    const float4 b1 = bt[j + 1];
#pragma unroll
    for (int k = 0; k < 8; ++k) {
      const float t0 = fmaf(nax[k], b0.x, fmaf(nay[k], b0.y, fmaf(naz[k], b0.z, b0.w)));
      const float t1 = fmaf(nax[k], b1.x, fmaf(nay[k], b1.y, fmaf(naz[k], b1.z, b1.w)));
      mn[k] = fminf(fminf(mn[k], t0), t1);
    }
  }
#pragma unroll
  for (int k = 0; k < 8; ++k) {
    const int idx = ab * 2048 + k * 256 + tid;
    const float v = fmaf(2.0f, mn[k], a2[k]);
    atomicMin(&minbuf[dir * NPTS + idx], __float_as_uint(v));
  }
}

__global__ __launch_bounds__(1024) void chamfer_reduce_u32_kernel(
    const unsigned int* __restrict__ minbuf, float* __restrict__ out) {
  __shared__ float red[1024];
  const int tid = threadIdx.x;
  float s = 0.0f;
  for (int j = tid; j < 2 * NPTS; j += 1024) s += __uint_as_float(minbuf[j]);
  red[tid] = s;
  __syncthreads();
  for (int off = 512; off > 0; off >>= 1) {
    if (tid < off) red[tid] += red[tid + off];
    __syncthreads();
  }
  if (tid == 0) out[0] = red[0] * (1.0f / (float)NPTS);
}

extern "C" void kernel_launch(void* const* d_in, const int* in_sizes, int n_in,
                              void* d_out, int out_size, void* d_ws, size_t ws_size,
                              hipStream_t stream) {
  const float* adv = (const float*)d_in[0];
  const float* ori = (const float*)d_in[1];
  float* out = (float*)d_out;

  const size_t needP = (size_t)2 * NPTS * 8 * sizeof(unsigned short);  // 512 KB
  if (ws_size >= needP) {
    unsigned short* partial = (unsigned short*)d_ws;
    chamfer_fused_kernel<<<512, 256, 0, stream>>>(adv, ori, partial);
    chamfer_reduce_bf16_kernel<<<1, 1024, 0, stream>>>(partial, out);
  } else {
    unsigned int* minbuf = (unsigned int*)d_ws;
    hipMemsetAsync(minbuf, 0x7F, (size_t)(2 * NPTS) * sizeof(unsigned int), stream);
    chamfer_valu_kernel<<<1024, 256, 0, stream>>>(adv, ori, minbuf);
    chamfer_reduce_u32_kernel<<<1, 1024, 0, stream>>>(minbuf, out);
  }
}